// Round 1
// baseline (2309.891 us; speedup 1.0000x reference)
//
#include <hip/hip_runtime.h>

// WarpingLayer_3stacks: trilinear scatter-splat (grid_push) of
// intensities = [x*mask, mask] into a 128^3 volume, coords = flow + meshgrid.
// Input spatial: 384 x 128 x 128. Output: [1, 2, 128, 128, 128] f32.
// Flow rescale factor is exactly 1 for all dims (383/383, 127/127, 127/127).

#define OS 128            // output size per dim
#define OS3 (128 * 128 * 128)

__global__ __launch_bounds__(256) void warp_push_kernel(
    const float* __restrict__ x,
    const float* __restrict__ flow,
    const float* __restrict__ mask,
    float* __restrict__ out,
    int N)
{
    int idx = blockIdx.x * blockDim.x + threadIdx.x;
    if (idx >= N) return;

    // source coords from linear index (W=128, H=128 -> shifts)
    int w = idx & 127;
    int h = (idx >> 7) & 127;
    int z = idx >> 14;

    // grid = flow + base (scale factor is identity)
    float gz = flow[idx]         + (float)z;
    float gy = flow[N + idx]     + (float)h;
    float gx = flow[2 * N + idx] + (float)w;

    float fz0 = floorf(gz), fy0 = floorf(gy), fx0 = floorf(gx);
    float fz = gz - fz0, fy = gy - fy0, fx = gx - fx0;
    int iz0 = (int)fz0, iy0 = (int)fy0, ix0 = (int)fx0;

    // replicate-clamped corner indices
    int izc0 = min(max(iz0,     0), OS - 1);
    int izc1 = min(max(iz0 + 1, 0), OS - 1);
    int iyc0 = min(max(iy0,     0), OS - 1);
    int iyc1 = min(max(iy0 + 1, 0), OS - 1);
    int ixc0 = min(max(ix0,     0), OS - 1);
    int ixc1 = min(max(ix0 + 1, 0), OS - 1);

    // merged corners: when both clamp to the same index, weights sum to 1.
    // z-merge covers ~2/3 of points (source z up to 383 vs output 127) and is
    // wave-uniform (z constant across 64 consecutive idx).
    bool zm = (izc0 == izc1);
    bool ym = (iyc0 == iyc1);
    bool xm = (ixc0 == ixc1);
    float wz0 = zm ? 1.0f : 1.0f - fz;
    float wy0 = ym ? 1.0f : 1.0f - fy;
    float wx0 = xm ? 1.0f : 1.0f - fx;

    float m  = mask[idx];
    float v0 = x[idx] * m;

    auto scatter_x = [&](int base, float wgt) {
        float w0 = wgt * wx0;
        int o0 = base | ixc0;
        atomicAdd(out + o0,        v0 * w0);
        atomicAdd(out + OS3 + o0,  m  * w0);
        if (!xm) {
            float w1 = wgt * fx;
            int o1 = base | ixc1;
            atomicAdd(out + o1,       v0 * w1);
            atomicAdd(out + OS3 + o1, m  * w1);
        }
    };
    auto scatter_y = [&](int base, float wgt) {
        scatter_x(base | (iyc0 << 7), wgt * wy0);
        if (!ym) scatter_x(base | (iyc1 << 7), wgt * fy);
    };
    scatter_y(izc0 << 14, wz0);
    if (!zm) scatter_y(izc1 << 14, fz);
}

extern "C" void kernel_launch(void* const* d_in, const int* in_sizes, int n_in,
                              void* d_out, int out_size, void* d_ws, size_t ws_size,
                              hipStream_t stream) {
    const float* x    = (const float*)d_in[0];
    const float* flow = (const float*)d_in[1];
    const float* mask = (const float*)d_in[2];
    float* out = (float*)d_out;

    int N = in_sizes[0];  // 384*128*128 = 6291456

    // d_out is poisoned before every call; scatter needs zeros.
    hipMemsetAsync(d_out, 0, (size_t)out_size * sizeof(float), stream);

    int threads = 256;
    int blocks = (N + threads - 1) / threads;
    warp_push_kernel<<<blocks, threads, 0, stream>>>(x, flow, mask, out, N);
}

// Round 2
// 1674.487 us; speedup vs baseline: 1.3795x; 1.3795x over previous
//
#include <hip/hip_runtime.h>

// WarpingLayer_3stacks: trilinear scatter-splat (grid_push) of
// intensities = [x*mask, mask] into a 128^3 volume, coords = flow + meshgrid.
// Input spatial: 384 x 128 x 128. Output: [1, 2, 128, 128, 128] f32.
//
// Structure: source z in [0,384) but output z caps at 127 -> all points with
// z >= ~128 clamp both z-corners to the z=127 plane (wz0+wz1 = 1). That plane
// received 33.6M atomics (1000/address) in R0 -> atomic-pipe backpressure
// (VALUBusy 0.65%). Fix: LDS-privatize the plane for the z>=128 region.

#define OS   128
#define OS3  (OS * OS * OS)
#define SRC_D 384
#define SRC_H 128
#define SRC_W 128
#define ZSPLIT 128                 // z < ZSPLIT: direct kernel; z >= ZSPLIT: plane kernel
#define NSRC (SRC_D * SRC_H * SRC_W)

// plane-kernel tiling
#define ZC 8                        // z-slabs per block
#define TH 16                       // h tile
#define TW 64                       // w tile
#define PAD 8                       // halo for flow displacement
#define LDSH (TH + 2 * PAD)         // 32
#define LDSW (TW + 2 * PAD)         // 80

// Generic 8-corner merged scatter with replicate clamping (matches reference).
__device__ __forceinline__ void scatter_global(float* __restrict__ out,
                                               float v0, float m,
                                               float gz, float gy, float gx)
{
    float fz0 = floorf(gz), fy0 = floorf(gy), fx0 = floorf(gx);
    float fz = gz - fz0, fy = gy - fy0, fx = gx - fx0;
    int iz0 = (int)fz0, iy0 = (int)fy0, ix0 = (int)fx0;

    int izc0 = min(max(iz0,     0), OS - 1);
    int izc1 = min(max(iz0 + 1, 0), OS - 1);
    int iyc0 = min(max(iy0,     0), OS - 1);
    int iyc1 = min(max(iy0 + 1, 0), OS - 1);
    int ixc0 = min(max(ix0,     0), OS - 1);
    int ixc1 = min(max(ix0 + 1, 0), OS - 1);

    bool zm = (izc0 == izc1), ym = (iyc0 == iyc1), xm = (ixc0 == ixc1);
    float wz0 = zm ? 1.0f : 1.0f - fz;
    float wy0 = ym ? 1.0f : 1.0f - fy;
    float wx0 = xm ? 1.0f : 1.0f - fx;

    auto scat_x = [&](int base, float wgt) {
        float w0 = wgt * wx0;
        int o0 = base | ixc0;
        atomicAdd(out + o0,       v0 * w0);
        atomicAdd(out + OS3 + o0, m  * w0);
        if (!xm) {
            float w1 = wgt * fx;
            int o1 = base | ixc1;
            atomicAdd(out + o1,       v0 * w1);
            atomicAdd(out + OS3 + o1, m  * w1);
        }
    };
    auto scat_y = [&](int base, float wgt) {
        scat_x(base | (iyc0 << 7), wgt * wy0);
        if (!ym) scat_x(base | (iyc1 << 7), wgt * fy);
    };
    scat_y(izc0 << 14, wz0);
    if (!zm) scat_y(izc1 << 14, fz);
}

// ---------------- direct kernel: source z in [0, ZSPLIT) ----------------
__global__ __launch_bounds__(256) void warp_push_direct(
    const float* __restrict__ x,
    const float* __restrict__ flow,
    const float* __restrict__ mask,
    float* __restrict__ out)
{
    int idx = blockIdx.x * blockDim.x + threadIdx.x;   // < ZSPLIT*128*128
    int w = idx & 127;
    int h = (idx >> 7) & 127;
    int z = idx >> 14;

    float gz = flow[idx]            + (float)z;
    float gy = flow[NSRC + idx]     + (float)h;
    float gx = flow[2 * NSRC + idx] + (float)w;

    float m  = mask[idx];
    float v0 = x[idx] * m;
    scatter_global(out, v0, m, gz, gy, gx);
}

// ------------- plane kernel: source z in [ZSPLIT, 384), LDS tile -------------
__global__ __launch_bounds__(256) void warp_push_plane(
    const float* __restrict__ x,
    const float* __restrict__ flow,
    const float* __restrict__ mask,
    float* __restrict__ out)
{
    __shared__ float tile[2][LDSH][LDSW];   // 20.5 KB

    int tid = threadIdx.x;
    // zero LDS
    for (int i = tid; i < 2 * LDSH * LDSW; i += 256)
        ((float*)tile)[i] = 0.0f;
    __syncthreads();

    int w0 = blockIdx.x * TW;
    int h0 = blockIdx.y * TH;
    int z0 = ZSPLIT + blockIdx.z * ZC;

    int dw  = tid & 63;        // lane -> consecutive w (coalesced)
    int sub = tid >> 6;        // 0..3

    const int hlo = h0 - PAD, wlo = w0 - PAD;

    for (int it = 0; it < (ZC * TH * TW) / 256; ++it) {  // 32 iters
        int pair = it * 4 + sub;       // 0..127 = dh(16) x dz(8)
        int dh = pair & (TH - 1);
        int dz = pair >> 4;
        int z = z0 + dz, h = h0 + dh, w = w0 + dw;
        int idx = (z * SRC_H + h) * SRC_W + w;

        float gz = flow[idx]            + (float)z;
        float gy = flow[NSRC + idx]     + (float)h;
        float gx = flow[2 * NSRC + idx] + (float)w;
        float m  = mask[idx];
        float v0 = x[idx] * m;

        float fy0 = floorf(gy), fx0 = floorf(gx);
        float fy = gy - fy0, fx = gx - fx0;
        int iy0 = (int)fy0, ix0 = (int)fx0;
        int iyc0 = min(max(iy0,     0), OS - 1);
        int iyc1 = min(max(iy0 + 1, 0), OS - 1);
        int ixc0 = min(max(ix0,     0), OS - 1);
        int ixc1 = min(max(ix0 + 1, 0), OS - 1);

        bool clampedZ = (gz >= (float)(OS - 1));   // iz0 >= 127 -> both corners = 127
        bool inTile = (iyc0 >= hlo) && (iyc1 < hlo + LDSH) &&
                      (ixc0 >= wlo) && (ixc1 < wlo + LDSW);

        if (clampedZ && inTile) {
            bool ym = (iyc0 == iyc1), xm = (ixc0 == ixc1);
            float wy0 = ym ? 1.0f : 1.0f - fy;
            float wx0 = xm ? 1.0f : 1.0f - fx;
            int r0 = iyc0 - hlo, r1 = iyc1 - hlo;
            int c0 = ixc0 - wlo, c1 = ixc1 - wlo;

            atomicAdd(&tile[0][r0][c0], v0 * wy0 * wx0);
            atomicAdd(&tile[1][r0][c0], m  * wy0 * wx0);
            if (!xm) {
                atomicAdd(&tile[0][r0][c1], v0 * wy0 * fx);
                atomicAdd(&tile[1][r0][c1], m  * wy0 * fx);
            }
            if (!ym) {
                atomicAdd(&tile[0][r1][c0], v0 * fy * wx0);
                atomicAdd(&tile[1][r1][c0], m  * fy * wx0);
                if (!xm) {
                    atomicAdd(&tile[0][r1][c1], v0 * fy * fx);
                    atomicAdd(&tile[1][r1][c1], m  * fy * fx);
                }
            }
        } else {
            // rare: z=128 boundary not fully clamped, or halo overflow
            scatter_global(out, v0, m, gz, gy, gx);
        }
    }

    __syncthreads();

    // flush LDS tile to the z=127 plane with one global atomic per cell
    const int planeBase = (OS - 1) << 14;   // z = 127
    for (int i = tid; i < 2 * LDSH * LDSW; i += 256) {
        int ch  = i / (LDSH * LDSW);
        int rem = i - ch * (LDSH * LDSW);
        int r = rem / LDSW;
        int c = rem - r * LDSW;
        int y = hlo + r, xo = wlo + c;
        if ((unsigned)y < OS && (unsigned)xo < OS) {
            float v = ((float*)tile)[i];
            if (v != 0.0f)
                atomicAdd(out + ch * OS3 + planeBase + (y << 7) + xo, v);
        }
    }
}

extern "C" void kernel_launch(void* const* d_in, const int* in_sizes, int n_in,
                              void* d_out, int out_size, void* d_ws, size_t ws_size,
                              hipStream_t stream) {
    const float* x    = (const float*)d_in[0];
    const float* flow = (const float*)d_in[1];
    const float* mask = (const float*)d_in[2];
    float* out = (float*)d_out;

    // d_out is poisoned before every call; scatter needs zeros.
    hipMemsetAsync(d_out, 0, (size_t)out_size * sizeof(float), stream);

    // direct region: z in [0,128) -> 2,097,152 points
    int n_direct = ZSPLIT * SRC_H * SRC_W;
    warp_push_direct<<<n_direct / 256, 256, 0, stream>>>(x, flow, mask, out);

    // plane region: z in [128,384): grid = (w tiles, h tiles, z chunks)
    dim3 grid(SRC_W / TW, SRC_H / TH, (SRC_D - ZSPLIT) / ZC);   // (2, 8, 32)
    warp_push_plane<<<grid, 256, 0, stream>>>(x, flow, mask, out);
}

// Round 3
// 516.019 us; speedup vs baseline: 4.4764x; 3.2450x over previous
//
#include <hip/hip_runtime.h>

// WarpingLayer_3stacks: trilinear scatter-splat (grid_push) of
// intensities = [x*mask, mask] into 128^3, coords = flow + meshgrid.
// Input 384x128x128. Output [1,2,128,128,128] f32.
//
// R1 lesson: global f32 atomicAdd ~22G/s memory-side is the wall (WRITE_SIZE
// ~25B/atomic, VALUBusy 0.4%). R2: z<128 region -> output-ownership gather:
// each block owns a disjoint output tile in LDS, processes all source points
// within halo 4, LDS-accumulates corners landing in its tile, plain-stores.
// Zero global atomics on the hot path. z>=128 keeps the z=127-plane LDS kernel.

#define OS    128
#define OS3   (OS * OS * OS)
#define SRC_D 384
#define SRC_H 128
#define SRC_W 128
#define NSRC  (SRC_D * SRC_H * SRC_W)
#define ZSPLIT 128

// ---- gather kernel tiling (owned output tile, full x extent) ----
#define TZ 4
#define TY 8
#define HALO 4            // covers |flow| < 4 per dim; P(miss) ~ 6e-5

// ---- plane kernel tiling ----
#define ZC 16             // z-slabs per block
#define TH 16
#define TW 64
#define PPAD 4
#define LDSH (TH + 2 * PPAD)   // 24
#define LDSW (TW + 2 * PPAD)   // 72

// Generic 8-corner merged scatter with replicate clamping (rare fallback).
__device__ __forceinline__ void scatter_global(float* __restrict__ out,
                                               float v0, float m,
                                               float gz, float gy, float gx)
{
    float fz0 = floorf(gz), fy0 = floorf(gy), fx0 = floorf(gx);
    float fz = gz - fz0, fy = gy - fy0, fx = gx - fx0;
    int iz0 = (int)fz0, iy0 = (int)fy0, ix0 = (int)fx0;

    int izc0 = min(max(iz0,     0), OS - 1);
    int izc1 = min(max(iz0 + 1, 0), OS - 1);
    int iyc0 = min(max(iy0,     0), OS - 1);
    int iyc1 = min(max(iy0 + 1, 0), OS - 1);
    int ixc0 = min(max(ix0,     0), OS - 1);
    int ixc1 = min(max(ix0 + 1, 0), OS - 1);

    bool zm = (izc0 == izc1), ym = (iyc0 == iyc1), xm = (ixc0 == ixc1);
    float wz0 = zm ? 1.0f : 1.0f - fz;
    float wy0 = ym ? 1.0f : 1.0f - fy;
    float wx0 = xm ? 1.0f : 1.0f - fx;

    auto scat_x = [&](int base, float wgt) {
        float w0 = wgt * wx0;
        int o0 = base | ixc0;
        atomicAdd(out + o0,       v0 * w0);
        atomicAdd(out + OS3 + o0, m  * w0);
        if (!xm) {
            float w1 = wgt * fx;
            int o1 = base | ixc1;
            atomicAdd(out + o1,       v0 * w1);
            atomicAdd(out + OS3 + o1, m  * w1);
        }
    };
    auto scat_y = [&](int base, float wgt) {
        scat_x(base | (iyc0 << 7), wgt * wy0);
        if (!ym) scat_x(base | (iyc1 << 7), wgt * fy);
    };
    scat_y(izc0 << 14, wz0);
    if (!zm) scat_y(izc1 << 14, fz);
}

// -------- gather kernel: source z in [0,128), output-tile ownership --------
// grid: (128/TZ, 128/TY) = (32, 16). Block owns out[z0:z0+TZ][y0:y0+TY][0:128].
__global__ __launch_bounds__(256) void warp_gather(
    const float* __restrict__ x,
    const float* __restrict__ flow,
    const float* __restrict__ mask,
    float* __restrict__ out,
    float* __restrict__ ovf,        // fallback target (ws partial, or out)
    int atomic_flush)               // 1 -> atomicAdd flush (no-ws mode)
{
    __shared__ float acc[2][TZ][TY][OS];   // 32 KB

    int tid = threadIdx.x;
    for (int i = tid; i < 2 * TZ * TY * OS; i += 256)
        ((float*)acc)[i] = 0.0f;
    __syncthreads();

    int z0 = blockIdx.x * TZ;
    int y0 = blockIdx.y * TY;
    int zlo = max(z0 - HALO, 0), zhi = min(z0 + TZ + HALO, ZSPLIT);
    int ylo = max(y0 - HALO, 0), yhi = min(y0 + TY + HALO, OS);

    int w  = tid & 127;
    int yh = tid >> 7;     // 0/1: two y-rows per iteration

    for (int zz = zlo; zz < zhi; ++zz) {
        for (int yb = ylo; yb < yhi; yb += 2) {
            int hh = yb + yh;
            if (hh >= yhi) continue;
            int idx = (zz << 14) + (hh << 7) + w;

            float gz = flow[idx]            + (float)zz;
            float gy = flow[NSRC + idx]     + (float)hh;
            float gx = flow[2 * NSRC + idx] + (float)w;
            float m  = mask[idx];
            float v  = x[idx] * m;

            float fz0 = floorf(gz), fy0 = floorf(gy), fx0 = floorf(gx);
            float fz = gz - fz0, fy = gy - fy0, fx = gx - fx0;
            int iz0 = (int)fz0, iy0 = (int)fy0, ix0 = (int)fx0;

            bool home = (zz >= z0) && (zz < z0 + TZ) &&
                        (hh >= y0) && (hh < y0 + TY);

            #pragma unroll
            for (int dz = 0; dz < 2; ++dz) {
                int cz = min(max(iz0 + dz, 0), OS - 1);
                float wz = dz ? fz : 1.0f - fz;
                #pragma unroll
                for (int dy = 0; dy < 2; ++dy) {
                    int cy = min(max(iy0 + dy, 0), OS - 1);
                    float wzy = wz * (dy ? fy : 1.0f - fy);
                    #pragma unroll
                    for (int dx = 0; dx < 2; ++dx) {
                        int cx = min(max(ix0 + dx, 0), OS - 1);
                        float wgt = wzy * (dx ? fx : 1.0f - fx);
                        bool near = (abs(cz - zz) <= HALO) && (abs(cy - hh) <= HALO);
                        if (near) {
                            if (cz >= z0 && cz < z0 + TZ && cy >= y0 && cy < y0 + TY) {
                                atomicAdd(&acc[0][cz - z0][cy - y0][cx], v * wgt);
                                atomicAdd(&acc[1][cz - z0][cy - y0][cx], m * wgt);
                            }
                        } else if (home) {
                            // rare (|flow|>=4): route to fallback target
                            int o = (cz << 14) + (cy << 7) + cx;
                            atomicAdd(ovf + o,       v * wgt);
                            atomicAdd(ovf + OS3 + o, m * wgt);
                        }
                    }
                }
            }
        }
    }

    __syncthreads();

    // flush owned tile: contiguous, coalesced
    for (int i = tid; i < 2 * TZ * TY * OS; i += 256) {
        int ch   = i >> 12;            // / (TZ*TY*OS) = 4096
        int rem  = i & 4095;
        int dz   = rem >> 10;          // / (TY*OS) = 1024
        int rem2 = rem & 1023;         // dy*128 + cx
        int o = ch * OS3 + ((z0 + dz) << 14) + (y0 << 7) + rem2;
        float val = ((float*)acc)[i];
        if (atomic_flush) atomicAdd(out + o, val);
        else              out[o] = val;
    }
}

// ------------- plane kernel: source z in [ZSPLIT,384), z=127 plane -------------
__global__ __launch_bounds__(256) void warp_push_plane(
    const float* __restrict__ x,
    const float* __restrict__ flow,
    const float* __restrict__ mask,
    float* __restrict__ out)
{
    __shared__ float tile[2][LDSH][LDSW];   // 13.8 KB

    int tid = threadIdx.x;
    for (int i = tid; i < 2 * LDSH * LDSW; i += 256)
        ((float*)tile)[i] = 0.0f;
    __syncthreads();

    int w0 = blockIdx.x * TW;
    int h0 = blockIdx.y * TH;
    int z0 = ZSPLIT + blockIdx.z * ZC;

    int dw  = tid & 63;
    int sub = tid >> 6;

    const int hlo = h0 - PPAD, wlo = w0 - PPAD;

    for (int it = 0; it < (ZC * TH * TW) / 256; ++it) {   // 64 iters
        int pair = it * 4 + sub;        // 0..255 = dh(16) x dz(16)
        int dh = pair & (TH - 1);
        int dz = pair >> 4;
        int z = z0 + dz, h = h0 + dh, w = w0 + dw;
        int idx = (z * SRC_H + h) * SRC_W + w;

        float gz = flow[idx]            + (float)z;
        float gy = flow[NSRC + idx]     + (float)h;
        float gx = flow[2 * NSRC + idx] + (float)w;
        float m  = mask[idx];
        float v0 = x[idx] * m;

        float fy0 = floorf(gy), fx0 = floorf(gx);
        float fy = gy - fy0, fx = gx - fx0;
        int iy0 = (int)fy0, ix0 = (int)fx0;
        int iyc0 = min(max(iy0,     0), OS - 1);
        int iyc1 = min(max(iy0 + 1, 0), OS - 1);
        int ixc0 = min(max(ix0,     0), OS - 1);
        int ixc1 = min(max(ix0 + 1, 0), OS - 1);

        bool clampedZ = (gz >= (float)(OS - 1));
        bool inTile = (iyc0 >= hlo) && (iyc1 < hlo + LDSH) &&
                      (ixc0 >= wlo) && (ixc1 < wlo + LDSW);

        if (clampedZ && inTile) {
            bool ym = (iyc0 == iyc1), xm = (ixc0 == ixc1);
            float wy0 = ym ? 1.0f : 1.0f - fy;
            float wx0 = xm ? 1.0f : 1.0f - fx;
            int r0 = iyc0 - hlo, r1 = iyc1 - hlo;
            int c0 = ixc0 - wlo, c1 = ixc1 - wlo;

            atomicAdd(&tile[0][r0][c0], v0 * wy0 * wx0);
            atomicAdd(&tile[1][r0][c0], m  * wy0 * wx0);
            if (!xm) {
                atomicAdd(&tile[0][r0][c1], v0 * wy0 * fx);
                atomicAdd(&tile[1][r0][c1], m  * wy0 * fx);
            }
            if (!ym) {
                atomicAdd(&tile[0][r1][c0], v0 * fy * wx0);
                atomicAdd(&tile[1][r1][c0], m  * fy * wx0);
                if (!xm) {
                    atomicAdd(&tile[0][r1][c1], v0 * fy * fx);
                    atomicAdd(&tile[1][r1][c1], m  * fy * fx);
                }
            }
        } else {
            scatter_global(out, v0, m, gz, gy, gx);
        }
    }

    __syncthreads();

    const int planeBase = (OS - 1) << 14;
    for (int i = tid; i < 2 * LDSH * LDSW; i += 256) {
        int ch  = i / (LDSH * LDSW);
        int rem = i - ch * (LDSH * LDSW);
        int r = rem / LDSW;
        int c = rem - r * LDSW;
        int y = hlo + r, xo = wlo + c;
        if ((unsigned)y < OS && (unsigned)xo < OS) {
            float v = ((float*)tile)[i];
            if (v != 0.0f)
                atomicAdd(out + ch * OS3 + planeBase + (y << 7) + xo, v);
        }
    }
}

// out += ws (applies the rare fallback partials)
__global__ __launch_bounds__(256) void combine_ws(float* __restrict__ out,
                                                  const float* __restrict__ ws)
{
    int i = blockIdx.x * blockDim.x + threadIdx.x;   // float4 index
    float4 a = ((float4*)out)[i];
    float4 b = ((const float4*)ws)[i];
    a.x += b.x; a.y += b.y; a.z += b.z; a.w += b.w;
    ((float4*)out)[i] = a;
}

extern "C" void kernel_launch(void* const* d_in, const int* in_sizes, int n_in,
                              void* d_out, int out_size, void* d_ws, size_t ws_size,
                              hipStream_t stream) {
    const float* x    = (const float*)d_in[0];
    const float* flow = (const float*)d_in[1];
    const float* mask = (const float*)d_in[2];
    float* out = (float*)d_out;

    const size_t outBytes = (size_t)2 * OS3 * sizeof(float);  // 16.78 MB
    const bool use_ws = ws_size >= outBytes;

    if (use_ws) {
        // fallback partials accumulate in ws; gather plain-stores the volume
        hipMemsetAsync(d_ws, 0, outBytes, stream);
    } else {
        hipMemsetAsync(d_out, 0, outBytes, stream);
    }

    float* ovf = use_ws ? (float*)d_ws : out;

    dim3 ggrid(OS / TZ, OS / TY);           // (32, 16) = 512 blocks
    warp_gather<<<ggrid, 256, 0, stream>>>(x, flow, mask, out, ovf,
                                           use_ws ? 0 : 1);

    dim3 pgrid(SRC_W / TW, SRC_H / TH, (SRC_D - ZSPLIT) / ZC);  // (2,8,16)
    warp_push_plane<<<pgrid, 256, 0, stream>>>(x, flow, mask, out);

    if (use_ws) {
        combine_ws<<<(2 * OS3 / 4) / 256, 256, 0, stream>>>(out, (const float*)d_ws);
    }
}